// Round 1
// baseline (239.702 us; speedup 1.0000x reference)
//
#include <hip/hip_runtime.h>

// Problem constants
#define BS   64
#define NA   900
#define NT   600
#define NSEL 300          // NA - NT
#define ED   256
#define AD   11
#define NC   10
#define SORTN 1024
#define CACHED_FLAG 0x40000000

// d_out layout (float offsets), outputs concatenated in return order:
// merged (BS,NA,ED+AD), new_conf (BS,NT), cf (BS,NT,ED), ca (BS,NT,AD)
#define OFF_MERGED  0
#define OFF_NEWCONF (BS * NA * (ED + AD))          // 15,379,200
#define OFF_CF      (OFF_NEWCONF + BS * NT)        // 15,417,600
#define OFF_CA      (OFF_CF + BS * NT * ED)        // 25,248,000

// Monotone map: f32 -> u32 such that u(a) < u(b) iff a < b
__device__ __forceinline__ unsigned int fkey(float x) {
    unsigned int u = __float_as_uint(x);
    return (u & 0x80000000u) ? ~u : (u | 0x80000000u);
}

// Ascending bitonic sort of SORTN 64-bit keys in LDS, 256 threads.
__device__ __forceinline__ void bitonic_sort(unsigned long long* keys, int tid) {
    for (int k = 2; k <= SORTN; k <<= 1) {
        for (int j = k >> 1; j > 0; j >>= 1) {
            __syncthreads();
            #pragma unroll
            for (int ii = 0; ii < SORTN / 256; ii++) {
                int i = tid + ii * 256;
                int ixj = i ^ j;
                if (ixj > i) {
                    unsigned long long a = keys[i];
                    unsigned long long b = keys[ixj];
                    bool up = ((i & k) == 0);
                    if ((a > b) == up) { keys[i] = b; keys[ixj] = a; }
                }
            }
        }
    }
    __syncthreads();
}

// One block per batch: conf_max -> top-300 (row map) -> conf_c -> top-600
__global__ __launch_bounds__(256) void topk_kernel(
    const float* __restrict__ confidence,   // (BS, NA, NC)
    const float* __restrict__ prev_conf,    // (BS, NT)
    const int*   __restrict__ mask,         // (BS)
    float*       __restrict__ new_conf_out, // (BS, NT)
    int*         __restrict__ src_map,      // ws (BS, NA): source row per feat row
    int*         __restrict__ idx2_out)     // ws (BS, NT): second top-k indices
{
    __shared__ float cmax[NA];
    __shared__ float cc[NA];
    __shared__ unsigned long long keys[SORTN];

    const int b   = blockIdx.x;
    const int tid = threadIdx.x;

    // 1) conf_max = max over NC
    for (int t = tid; t < NA; t += 256) {
        const float* cp = confidence + ((size_t)b * NA + t) * NC;
        float m = cp[0];
        #pragma unroll
        for (int k = 1; k < NC; k++) m = fmaxf(m, cp[k]);
        cmax[t] = m;
    }
    __syncthreads();

    // 2) sort1 keys: descending value, ascending index on ties (jax top_k)
    for (int i = tid; i < SORTN; i += 256) {
        keys[i] = (i < NA)
            ? ((((unsigned long long)(~fkey(cmax[i]))) << 32) | (unsigned int)i)
            : 0xFFFFFFFFFFFFFFFFull;
    }
    bitonic_sort(keys, tid);

    // 3) build src_map; compute conf_c (sigmoid in double, round once; decay on first NT)
    const int mk = mask[b];
    for (int t = tid; t < NA; t += 256) {
        int s;
        if (mk) {
            s = (t < NT) ? (t | CACHED_FLAG)
                         : (int)(keys[t - NT] & 0xFFFFFFFFull);  // top-300 in desc order
        } else {
            s = t;
        }
        src_map[(size_t)b * NA + t] = s;

        float  x = cmax[t];
        double d = 1.0 / (1.0 + exp(-(double)x));
        float  c = (float)d;
        if (t < NT) c = fmaxf(prev_conf[(size_t)b * NT + t] * 0.6f, c);
        cc[t] = c;
    }
    __syncthreads();  // all reads of keys (sort1) done before rebuilding

    // 4) sort2 over conf_c
    for (int i = tid; i < SORTN; i += 256) {
        keys[i] = (i < NA)
            ? ((((unsigned long long)(~fkey(cc[i]))) << 32) | (unsigned int)i)
            : 0xFFFFFFFFFFFFFFFFull;
    }
    bitonic_sort(keys, tid);

    // 5) emit new_conf + idx2 (top-600, desc, stable)
    for (int j = tid; j < NT; j += 256) {
        int r = (int)(keys[j] & 0xFFFFFFFFull);
        idx2_out[(size_t)b * NT + j]     = r;
        new_conf_out[(size_t)b * NT + j] = cc[r];
    }
}

// One wave (64 lanes) per output row. Rows 0..NA-1: merged; NA..NA+NT-1: cf/ca.
__global__ __launch_bounds__(256) void gather_kernel(
    const float* __restrict__ inst_f,   // (BS, NA, ED)
    const float* __restrict__ anchor,   // (BS, NA, AD)
    const float* __restrict__ cached_f, // (BS, NT, ED)
    const float* __restrict__ cached_a, // (BS, NT, AD)
    const int*   __restrict__ src_map,  // (BS, NA)
    const int*   __restrict__ idx2,     // (BS, NT)
    float*       __restrict__ out)
{
    const int wave = threadIdx.x >> 6;
    const int lane = threadIdx.x & 63;
    const int gr   = blockIdx.x * 4 + wave;
    if (gr >= BS * (NA + NT)) return;

    const int b = gr / (NA + NT);
    const int t = gr - b * (NA + NT);

    // Resolve source row in feat-space, then through src_map to a real array row.
    int row = (t < NA) ? t : idx2[(size_t)b * NT + (t - NA)];
    const int s = src_map[(size_t)b * NA + row];

    const float* fsrc;
    const float* asrc;
    if (s & CACHED_FLAG) {
        const int r = s & 0xFFFF;
        fsrc = cached_f + ((size_t)b * NT + r) * ED;
        asrc = cached_a + ((size_t)b * NT + r) * AD;
    } else {
        fsrc = inst_f + ((size_t)b * NA + s) * ED;
        asrc = anchor + ((size_t)b * NA + s) * AD;
    }

    if (t < NA) {
        // merged row: 267 floats, row base not 16B-aligned -> coalesced scalar copies
        float* orow = out + OFF_MERGED + ((size_t)b * NA + t) * (ED + AD);
        #pragma unroll
        for (int k = 0; k < ED / 64; k++) {
            orow[lane + 64 * k] = fsrc[lane + 64 * k];
        }
        if (lane < AD) orow[ED + lane] = asrc[lane];
    } else {
        const int j = t - NA;
        // cf row: 256 floats, 16B-aligned both sides -> float4
        float4*       crow = (float4*)(out + OFF_CF + ((size_t)b * NT + j) * ED);
        const float4* f4   = (const float4*)fsrc;
        crow[lane] = f4[lane];
        if (lane < AD) out[OFF_CA + ((size_t)b * NT + j) * AD + lane] = asrc[lane];
    }
}

extern "C" void kernel_launch(void* const* d_in, const int* in_sizes, int n_in,
                              void* d_out, int out_size, void* d_ws, size_t ws_size,
                              hipStream_t stream) {
    const float* inst_f = (const float*)d_in[0];
    const float* anchor = (const float*)d_in[1];
    const float* conf   = (const float*)d_in[2];
    const float* cach_f = (const float*)d_in[3];
    const float* cach_a = (const float*)d_in[4];
    const float* prevc  = (const float*)d_in[5];
    const int*   mask   = (const int*)d_in[6];
    float* out = (float*)d_out;

    int* src_map = (int*)d_ws;              // BS*NA ints
    int* idx2    = src_map + BS * NA;       // BS*NT ints

    topk_kernel<<<BS, 256, 0, stream>>>(conf, prevc, mask,
                                        out + OFF_NEWCONF, src_map, idx2);

    const int nrows = BS * (NA + NT);
    gather_kernel<<<(nrows + 3) / 4, 256, 0, stream>>>(
        inst_f, anchor, cach_f, cach_a, src_map, idx2, out);
}

// Round 2
// 213.111 us; speedup vs baseline: 1.1248x; 1.1248x over previous
//
#include <hip/hip_runtime.h>

// Problem constants
#define BS   64
#define NA   900
#define NT   600
#define NSEL 300          // NA - NT
#define ED   256
#define AD   11
#define NC   10
#define SORTN 1024
#define CACHED_FLAG 0x40000000

// d_out layout (float offsets), outputs concatenated in return order:
// merged (BS,NA,ED+AD), new_conf (BS,NT), cf (BS,NT,ED), ca (BS,NT,AD)
#define OFF_MERGED  0
#define OFF_NEWCONF (BS * NA * (ED + AD))          // 15,379,200
#define OFF_CF      (OFF_NEWCONF + BS * NT)        // 15,417,600
#define OFF_CA      (OFF_CF + BS * NT * ED)        // 25,248,000

// Monotone map: f32 -> u32 such that u(a) < u(b) iff a < b
__device__ __forceinline__ unsigned int fkey(float x) {
    unsigned int u = __float_as_uint(x);
    return (u & 0x80000000u) ? ~u : (u | 0x80000000u);
}

__device__ __forceinline__ unsigned long long shfl_xor64(unsigned long long v, int m) {
    return (unsigned long long)__shfl_xor((long long)v, m, 64);
}

// Register-resident bitonic sort of 1024 keys across 1024 threads.
// Thread i owns key i. j<64 phases: __shfl_xor (no barrier). j>=64: LDS exchange.
// Keys unique (index in low bits) so min/max compare-exchange is exact.
__device__ __forceinline__ void sort1024(unsigned long long& key, int i,
                                         unsigned long long* lds) {
    for (int k = 2; k <= SORTN; k <<= 1) {
        for (int j = k >> 1; j > 0; j >>= 1) {
            unsigned long long partner;
            if (j >= 64) {
                __syncthreads();
                lds[i] = key;
                __syncthreads();
                partner = lds[i ^ j];
            } else {
                partner = shfl_xor64(key, j);
            }
            const bool up      = ((i & k) == 0);
            const bool lower   = ((i & j) == 0);
            const bool keepmin = (lower == up);
            const bool pgt     = (key > partner);
            key = (keepmin == pgt) ? partner : key;
        }
    }
}

// One block (1024 threads) per batch: conf_max -> top-300 (row map) -> conf_c -> top-600
__global__ __launch_bounds__(1024) void topk_kernel(
    const float* __restrict__ confidence,   // (BS, NA, NC)
    const float* __restrict__ prev_conf,    // (BS, NT)
    const int*   __restrict__ mask,         // (BS)
    float*       __restrict__ new_conf_out, // (BS, NT)
    int*         __restrict__ src_map,      // ws (BS, NA): source row per feat row
    int*         __restrict__ idx2_out)     // ws (BS, NT): second top-k indices
{
    __shared__ unsigned long long keys[SORTN];   // exchange buffer; reused as int[] rank
    __shared__ float cc_s[NA];

    const int b = blockIdx.x;
    const int i = threadIdx.x;

    // 1) conf_max = max over NC (thread i owns row i)
    float cmax = 0.0f;
    if (i < NA) {
        const float* cp = confidence + ((size_t)b * NA + i) * NC;
        float m = cp[0];
        #pragma unroll
        for (int k = 1; k < NC; k++) m = fmaxf(m, cp[k]);
        cmax = m;
    }

    // 2) sort1: descending value, ascending index on ties (jax top_k order)
    unsigned long long key = (i < NA)
        ? ((((unsigned long long)(~fkey(cmax))) << 32) | (unsigned int)i)
        : 0xFFFFFFFFFFFFFFFFull;
    sort1024(key, i, keys);

    // 3) publish rank->index, build src_map
    __syncthreads();                       // last sort reads done before reuse
    int* rank = (int*)keys;
    rank[i] = (int)(key & 0xFFFFFFFFull);
    __syncthreads();

    const int mk = mask[b];
    if (i < NA) {
        int s;
        if (mk) {
            s = (i < NT) ? (i | CACHED_FLAG) : rank[i - NT];  // top-300, desc order
        } else {
            s = i;
        }
        src_map[(size_t)b * NA + i] = s;
    }

    // 4) conf_c: sigmoid in double (round once), decay-max on first NT
    float c = 0.0f;
    if (i < NA) {
        double d = 1.0 / (1.0 + exp(-(double)cmax));
        c = (float)d;
        if (i < NT) c = fmaxf(prev_conf[(size_t)b * NT + i] * 0.6f, c);
        cc_s[i] = c;
    }
    __syncthreads();                       // rank reads done; cc_s visible

    // 5) sort2 over conf_c
    key = (i < NA)
        ? ((((unsigned long long)(~fkey(c))) << 32) | (unsigned int)i)
        : 0xFFFFFFFFFFFFFFFFull;
    sort1024(key, i, keys);

    // 6) emit new_conf + idx2 (thread i holds descending rank i)
    if (i < NT) {
        int r = (int)(key & 0xFFFFFFFFull);
        idx2_out[(size_t)b * NT + i]     = r;
        new_conf_out[(size_t)b * NT + i] = cc_s[r];
    }
}

// One wave (64 lanes) per output row. Rows 0..NA-1: merged; NA..NA+NT-1: cf/ca.
__global__ __launch_bounds__(256) void gather_kernel(
    const float* __restrict__ inst_f,   // (BS, NA, ED)
    const float* __restrict__ anchor,   // (BS, NA, AD)
    const float* __restrict__ cached_f, // (BS, NT, ED)
    const float* __restrict__ cached_a, // (BS, NT, AD)
    const int*   __restrict__ src_map,  // (BS, NA)
    const int*   __restrict__ idx2,     // (BS, NT)
    float*       __restrict__ out)
{
    const int wave = threadIdx.x >> 6;
    const int lane = threadIdx.x & 63;
    const int gr   = blockIdx.x * 4 + wave;
    if (gr >= BS * (NA + NT)) return;

    const int b = gr / (NA + NT);
    const int t = gr - b * (NA + NT);

    // Resolve source row in feat-space, then through src_map to a real array row.
    int row = (t < NA) ? t : idx2[(size_t)b * NT + (t - NA)];
    const int s = src_map[(size_t)b * NA + row];

    const float* fsrc;
    const float* asrc;
    if (s & CACHED_FLAG) {
        const int r = s & 0xFFFF;
        fsrc = cached_f + ((size_t)b * NT + r) * ED;
        asrc = cached_a + ((size_t)b * NT + r) * AD;
    } else {
        fsrc = inst_f + ((size_t)b * NA + s) * ED;
        asrc = anchor + ((size_t)b * NA + s) * AD;
    }

    if (t < NA) {
        // merged row: 267 floats. Src is 16B-aligned -> one float4 load per lane;
        // dst rows are 1068 B (not 16B-aligned) -> 4 scalar stores (wave still
        // covers a contiguous 1024 B span per 4-instruction group).
        float* orow = out + OFF_MERGED + ((size_t)b * NA + t) * (ED + AD);
        const float4 v = ((const float4*)fsrc)[lane];
        orow[4 * lane + 0] = v.x;
        orow[4 * lane + 1] = v.y;
        orow[4 * lane + 2] = v.z;
        orow[4 * lane + 3] = v.w;
        if (lane < AD) orow[ED + lane] = asrc[lane];
    } else {
        const int j = t - NA;
        // cf row: 256 floats, 16B-aligned both sides -> float4
        float4*       crow = (float4*)(out + OFF_CF + ((size_t)b * NT + j) * ED);
        const float4* f4   = (const float4*)fsrc;
        crow[lane] = f4[lane];
        if (lane < AD) out[OFF_CA + ((size_t)b * NT + j) * AD + lane] = asrc[lane];
    }
}

extern "C" void kernel_launch(void* const* d_in, const int* in_sizes, int n_in,
                              void* d_out, int out_size, void* d_ws, size_t ws_size,
                              hipStream_t stream) {
    const float* inst_f = (const float*)d_in[0];
    const float* anchor = (const float*)d_in[1];
    const float* conf   = (const float*)d_in[2];
    const float* cach_f = (const float*)d_in[3];
    const float* cach_a = (const float*)d_in[4];
    const float* prevc  = (const float*)d_in[5];
    const int*   mask   = (const int*)d_in[6];
    float* out = (float*)d_out;

    int* src_map = (int*)d_ws;              // BS*NA ints
    int* idx2    = src_map + BS * NA;       // BS*NT ints

    topk_kernel<<<BS, 1024, 0, stream>>>(conf, prevc, mask,
                                         out + OFF_NEWCONF, src_map, idx2);

    const int nrows = BS * (NA + NT);
    gather_kernel<<<(nrows + 3) / 4, 256, 0, stream>>>(
        inst_f, anchor, cach_f, cach_a, src_map, idx2, out);
}

// Round 3
// 209.256 us; speedup vs baseline: 1.1455x; 1.0184x over previous
//
#include <hip/hip_runtime.h>

// Problem constants
#define BS   64
#define NA   900
#define NT   600
#define NSEL 300          // NA - NT
#define ED   256
#define AD   11
#define NC   10
#define SORTN 1024
#define CACHED_FLAG 0x40000000

// d_out layout (float offsets), outputs concatenated in return order:
// merged (BS,NA,ED+AD), new_conf (BS,NT), cf (BS,NT,ED), ca (BS,NT,AD)
#define OFF_MERGED  0
#define OFF_NEWCONF (BS * NA * (ED + AD))          // 15,379,200
#define OFF_CF      (OFF_NEWCONF + BS * NT)        // 15,417,600
#define OFF_CA      (OFF_CF + BS * NT * ED)        // 25,248,000

// Monotone map: f32 -> u32 such that u(a) < u(b) iff a < b
__device__ __forceinline__ unsigned int fkey(float x) {
    unsigned int u = __float_as_uint(x);
    return (u & 0x80000000u) ? ~u : (u | 0x80000000u);
}

__device__ __forceinline__ unsigned long long shfl_xor64(unsigned long long v, int m) {
    return (unsigned long long)__shfl_xor((long long)v, m, 64);
}

// Register-resident bitonic sort of 1024 keys across 1024 threads.
// Thread i owns key i. j<64 phases: __shfl_xor (no barrier). j>=64: LDS exchange.
// Keys unique (index in low bits) so min/max compare-exchange is exact.
__device__ __forceinline__ void sort1024(unsigned long long& key, int i,
                                         unsigned long long* lds) {
    for (int k = 2; k <= SORTN; k <<= 1) {
        for (int j = k >> 1; j > 0; j >>= 1) {
            unsigned long long partner;
            if (j >= 64) {
                __syncthreads();
                lds[i] = key;
                __syncthreads();
                partner = lds[i ^ j];
            } else {
                partner = shfl_xor64(key, j);
            }
            const bool up      = ((i & k) == 0);
            const bool lower   = ((i & j) == 0);
            const bool keepmin = (lower == up);
            const bool pgt     = (key > partner);
            key = (keepmin == pgt) ? partner : key;
        }
    }
}

// One block (1024 threads) per batch:
// conf_max -> sort1 (top-300 row map) -> conf_c -> sort2 (new_conf + pos2 inverse map)
__global__ __launch_bounds__(1024) void topk_kernel(
    const float* __restrict__ confidence,   // (BS, NA, NC)
    const float* __restrict__ prev_conf,    // (BS, NT)
    const int*   __restrict__ mask,         // (BS)
    float*       __restrict__ new_conf_out, // (BS, NT)
    int*         __restrict__ src_map,      // ws (BS, NA): source row per feat row
    int*         __restrict__ pos2)         // ws (BS, NA): feat row -> cf rank, or -1
{
    __shared__ unsigned long long keys[SORTN];   // exchange buffer; reused as int[] rank
    __shared__ float cc_s[NA];

    const int b = blockIdx.x;
    const int i = threadIdx.x;

    // 1) conf_max = max over NC (thread i owns row i)
    float cmax = 0.0f;
    if (i < NA) {
        const float* cp = confidence + ((size_t)b * NA + i) * NC;
        float m = cp[0];
        #pragma unroll
        for (int k = 1; k < NC; k++) m = fmaxf(m, cp[k]);
        cmax = m;
    }

    // 2) sort1: descending value, ascending index on ties (jax top_k order)
    unsigned long long key = (i < NA)
        ? ((((unsigned long long)(~fkey(cmax))) << 32) | (unsigned int)i)
        : 0xFFFFFFFFFFFFFFFFull;
    sort1024(key, i, keys);

    // 3) publish rank->index, build src_map
    __syncthreads();                       // last sort reads done before reuse
    int* rank = (int*)keys;
    rank[i] = (int)(key & 0xFFFFFFFFull);
    __syncthreads();

    const int mk = mask[b];
    if (i < NA) {
        int s;
        if (mk) {
            s = (i < NT) ? (i | CACHED_FLAG) : rank[i - NT];  // top-300, desc order
        } else {
            s = i;
        }
        src_map[(size_t)b * NA + i] = s;
    }

    // 4) conf_c: sigmoid in double (round once), decay-max on first NT
    float c = 0.0f;
    if (i < NA) {
        double d = 1.0 / (1.0 + exp(-(double)cmax));
        c = (float)d;
        if (i < NT) c = fmaxf(prev_conf[(size_t)b * NT + i] * 0.6f, c);
        cc_s[i] = c;
    }
    __syncthreads();                       // rank reads done; cc_s visible

    // 5) sort2 over conf_c
    key = (i < NA)
        ? ((((unsigned long long)(~fkey(c))) << 32) | (unsigned int)i)
        : 0xFFFFFFFFFFFFFFFFull;
    sort1024(key, i, keys);

    // 6) emit new_conf + inverse map pos2 (thread i holds descending rank i).
    //    Ranks [0,NA) hold each real row exactly once; padding sorts strictly last
    //    (conf_c in (0,1), padding key value is the NaN bit pattern -> unique max).
    if (i < NT) {
        int r = (int)(key & 0xFFFFFFFFull);
        new_conf_out[(size_t)b * NT + i] = cc_s[r];
        pos2[(size_t)b * NA + r] = i;
    } else if (i < NA) {
        int r = (int)(key & 0xFFFFFFFFull);
        pos2[(size_t)b * NA + r] = -1;
    }
}

// One wave (64 lanes) per feat row. Writes merged row; if the row is in the
// second top-k (pos2 >= 0), also writes the cf/ca row from the same registers.
__global__ __launch_bounds__(256) void gather_kernel(
    const float* __restrict__ inst_f,   // (BS, NA, ED)
    const float* __restrict__ anchor,   // (BS, NA, AD)
    const float* __restrict__ cached_f, // (BS, NT, ED)
    const float* __restrict__ cached_a, // (BS, NT, AD)
    const int*   __restrict__ src_map,  // (BS, NA)
    const int*   __restrict__ pos2,     // (BS, NA)
    float*       __restrict__ out)
{
    const int wave = threadIdx.x >> 6;
    const int lane = threadIdx.x & 63;
    const int gr   = blockIdx.x * 4 + wave;
    if (gr >= BS * NA) return;

    const int b = gr / NA;
    const int t = gr - b * NA;

    // Independent loads (chain depth 2: map -> data).
    const int s = src_map[(size_t)b * NA + t];
    const int p = pos2[(size_t)b * NA + t];

    const float* fsrc;
    const float* asrc;
    if (s & CACHED_FLAG) {
        const int r = s & 0xFFFF;
        fsrc = cached_f + ((size_t)b * NT + r) * ED;
        asrc = cached_a + ((size_t)b * NT + r) * AD;
    } else {
        fsrc = inst_f + ((size_t)b * NA + s) * ED;
        asrc = anchor + ((size_t)b * NA + s) * AD;
    }

    // Source feature row: 16B-aligned -> one float4 load per lane.
    const float4 v = ((const float4*)fsrc)[lane];
    float av = 0.0f;
    if (lane < AD) av = asrc[lane];

    // merged row: 267 floats, 1068 B pitch (not 16B-aligned) -> scalar stores;
    // a wave's 4 stores still cover one contiguous 1024 B span.
    float* orow = out + OFF_MERGED + ((size_t)b * NA + t) * (ED + AD);
    orow[4 * lane + 0] = v.x;
    orow[4 * lane + 1] = v.y;
    orow[4 * lane + 2] = v.z;
    orow[4 * lane + 3] = v.w;
    if (lane < AD) orow[ED + lane] = av;

    // cf/ca row (aligned) from the same registers — no second read of the source.
    if (p >= 0) {
        float4* crow = (float4*)(out + OFF_CF + ((size_t)b * NT + p) * ED);
        crow[lane] = v;
        if (lane < AD) out[OFF_CA + ((size_t)b * NT + p) * AD + lane] = av;
    }
}

extern "C" void kernel_launch(void* const* d_in, const int* in_sizes, int n_in,
                              void* d_out, int out_size, void* d_ws, size_t ws_size,
                              hipStream_t stream) {
    const float* inst_f = (const float*)d_in[0];
    const float* anchor = (const float*)d_in[1];
    const float* conf   = (const float*)d_in[2];
    const float* cach_f = (const float*)d_in[3];
    const float* cach_a = (const float*)d_in[4];
    const float* prevc  = (const float*)d_in[5];
    const int*   mask   = (const int*)d_in[6];
    float* out = (float*)d_out;

    int* src_map = (int*)d_ws;              // BS*NA ints
    int* pos2    = src_map + BS * NA;       // BS*NA ints

    topk_kernel<<<BS, 1024, 0, stream>>>(conf, prevc, mask,
                                         out + OFF_NEWCONF, src_map, pos2);

    const int nrows = BS * NA;
    gather_kernel<<<(nrows + 3) / 4, 256, 0, stream>>>(
        inst_f, anchor, cach_f, cach_a, src_map, pos2, out);
}